// Round 11
// baseline (100.885 us; speedup 1.0000x reference)
//
#include <hip/hip_runtime.h>
#include <hip/hip_bf16.h>
#include <stdint.h>

#define BB   8
#define CIN  256
#define COUT 128
#define NN   4096

using f32x4  = __attribute__((ext_vector_type(4))) float;
using bf16x8 = __attribute__((ext_vector_type(8))) __bf16;
using u16x8  = __attribute__((ext_vector_type(8))) unsigned short;

static __device__ __forceinline__ unsigned short f2bf(float f) {
    unsigned int u = __builtin_bit_cast(unsigned int, f);
    u += 0x7FFFu + ((u >> 16) & 1u);
    return (unsigned short)(u >> 16);
}
static __device__ __forceinline__ float bf2f(unsigned short u) {
    return __builtin_bit_cast(float, (unsigned int)u << 16);
}
static __device__ __forceinline__ ushort4 pack4(float a, float b, float c, float d) {
    ushort4 r; r.x=f2bf(a); r.y=f2bf(b); r.z=f2bf(c); r.w=f2bf(d); return r;
}
#define MFMA(a,b,c) __builtin_amdgcn_mfma_f32_16x16x32_bf16((a),(b),(c),0,0,0)

static __device__ __forceinline__ int sw256(int r, int c) { return (r*256 + c) ^ ((r&7)<<3); }
static __device__ __forceinline__ int sw128(int r, int c) { return (r*128 + c) ^ ((r&7)<<3); }

// ============ kA: 256 blocks x 512 thr. chunk n=128, LDS 64KB. Gram partial Sp[bid] (256x256 bf16) + Rp ====
__global__ __launch_bounds__(512) void kA(
    const float* __restrict__ x,
    unsigned short* __restrict__ Sp, float* __restrict__ Rp)
{
    __shared__ __align__(16) unsigned short SH[32768];   // 64 KB: X [256c][128n] swz; later S-half [256][128]
    int bid = blockIdx.x;
    int b = bid >> 5, ch = bid & 31;
    int n0 = ch * 128;
    int t = threadIdx.x, lane = t & 63, wv = t >> 6;
    int lr = lane & 15, lg = lane >> 4;

    // stage: 16 loads in flight, then convert+write. half-wave reads 512B contiguous per row.
    {
        int n4 = (t & 31) * 4;            // 0..124
        int c0 = t >> 5;                  // 0..15
        const float* xb = x + (size_t)b*CIN*NN + n0 + n4;
        float4 v[16];
        #pragma unroll
        for (int i = 0; i < 16; ++i)
            v[i] = *(const float4*)(xb + (size_t)(c0 + i*16)*NN);
        #pragma unroll
        for (int i = 0; i < 16; ++i) {
            int c = c0 + i*16;
            *(ushort4*)&SH[sw128(c, n4)] = pack4(v[i].x, v[i].y, v[i].z, v[i].w);
        }
    }
    __syncthreads();

    int wr = wv >> 1, wc = wv & 1;      // 4x2: tile 64c1 x 128c2
    f32x4 acc[4][8];
    #pragma unroll
    for (int i = 0; i < 4; ++i)
        #pragma unroll
        for (int j = 0; j < 8; ++j) acc[i][j] = (f32x4){0.f,0.f,0.f,0.f};
    #pragma unroll
    for (int ks = 0; ks < 4; ++ks) {    // K = 128
        bf16x8 af[4], bfr[8];
        #pragma unroll
        for (int mi = 0; mi < 4; ++mi) {
            int row = wr*64 + mi*16 + lr;
            af[mi] = __builtin_bit_cast(bf16x8, *(const u16x8*)&SH[sw128(row, ks*32 + lg*8)]);
        }
        #pragma unroll
        for (int ni = 0; ni < 8; ++ni) {
            int row = wc*128 + ni*16 + lr;
            bfr[ni] = __builtin_bit_cast(bf16x8, *(const u16x8*)&SH[sw128(row, ks*32 + lg*8)]);
        }
        #pragma unroll
        for (int mi = 0; mi < 4; ++mi)
            #pragma unroll
            for (int ni = 0; ni < 8; ++ni)
                acc[mi][ni] = MFMA(af[mi], bfr[ni], acc[mi][ni]);
    }
    // row-sums from staged LDS (before overwrite)
    if (t < 256) {
        float s = 0.f;
        #pragma unroll
        for (int q = 0; q < 16; ++q) {
            u16x8 vv = *(const u16x8*)&SH[sw128(t, q*8)];
            #pragma unroll
            for (int e = 0; e < 8; ++e) s += bf2f(vv[e]);
        }
        Rp[bid*256 + t] = s;
    }

    // two-pass acc dump + coalesced store (c2 halves; SH reused as [256][128])
    unsigned short* dst = Sp + (size_t)bid * 65536;
    #pragma unroll
    for (int p = 0; p < 2; ++p) {
        __syncthreads();
        if (wc == p) {
            #pragma unroll
            for (int mi = 0; mi < 4; ++mi)
                #pragma unroll
                for (int ni = 0; ni < 8; ++ni)
                    #pragma unroll
                    for (int j = 0; j < 4; ++j) {
                        int c1 = wr*64 + mi*16 + lg*4 + j;
                        int c2l = ni*16 + lr;
                        SH[sw128(c1, c2l)] = f2bf(acc[mi][ni][j]);
                    }
        }
        __syncthreads();
        #pragma unroll
        for (int i = t; i < 4096; i += 512) {
            int row = i >> 4, q = i & 15;
            *(u16x8*)(dst + row*256 + p*128 + ((q ^ (row&7)) * 8)) = *(const u16x8*)&SH[row*128 + q*8];
        }
    }
}

// ============ kR: 138 blocks x 512.
//   0-127 : Sbf[b] = sum 32 partials; 128-135: rv
//   136   : Abf = Ww*Gw, a1 = Ww*gb, zero stats
//   137   : CmT = Tw^T*Pw, c1v, p2, sigma ============
__global__ __launch_bounds__(512) void kR(
    const unsigned short* __restrict__ Sp, const float* __restrict__ Rp,
    const float* __restrict__ Wwf, const float* __restrict__ gwf,
    const float* __restrict__ twf, const float* __restrict__ pwf,
    const float* __restrict__ gbv, const float* __restrict__ pbv, const float* __restrict__ tbv,
    unsigned short* __restrict__ Sbf, float* __restrict__ rv,
    unsigned short* __restrict__ Abf, unsigned short* __restrict__ CmT,
    float* __restrict__ a1, float* __restrict__ c1v, float* __restrict__ p2,
    float* __restrict__ params, float* __restrict__ stats)
{
    __shared__ __align__(16) unsigned short Ls[32768];
    __shared__ __align__(16) unsigned short Rs[32768];
    int bid = blockIdx.x;
    int t = threadIdx.x, lane = t & 63, wv = t >> 6;
    int lr = lane & 15, lg = lane >> 4;

    if (bid < 128) {
        int b = bid >> 4, sl = bid & 15;
        int base = sl*4096 + t*8;
        float s[8] = {0.f,0.f,0.f,0.f,0.f,0.f,0.f,0.f};
        #pragma unroll
        for (int i = 0; i < 32; ++i) {
            u16x8 v = *(const u16x8*)(Sp + (size_t)(b*32 + i)*65536 + base);
            #pragma unroll
            for (int e = 0; e < 8; ++e) s[e] += bf2f(v[e]);
        }
        u16x8 o;
        #pragma unroll
        for (int e = 0; e < 8; ++e) o[e] = f2bf(s[e]);
        *(u16x8*)(Sbf + (size_t)b*65536 + base) = o;
        return;
    }
    if (bid < 136) {
        int b = bid - 128;
        if (t < 256) {
            float s = 0.f;
            #pragma unroll
            for (int i = 0; i < 32; ++i) s += Rp[(b*32 + i)*256 + t];
            rv[b*256 + t] = s;
        }
        return;
    }

    if (bid == 136) {
        for (int i = t; i < 8192; i += 512) {
            int flat = i*4, r = flat >> 7, c = flat & 127;
            float4 f = *(const float4*)(Wwf + flat);
            *(ushort4*)&Ls[sw128(r, c)] = pack4(f.x, f.y, f.z, f.w);
        }
        {
            int c = lane * 4;  int k4 = wv * 4;
            #pragma unroll
            for (int rep = 0; rep < 4; ++rep) {
                int kb = rep*32 + k4;
                float4 f0 = *(const float4*)(gwf + (size_t)(kb+0)*256 + c);
                float4 f1 = *(const float4*)(gwf + (size_t)(kb+1)*256 + c);
                float4 f2 = *(const float4*)(gwf + (size_t)(kb+2)*256 + c);
                float4 f3 = *(const float4*)(gwf + (size_t)(kb+3)*256 + c);
                *(ushort4*)&Rs[sw128(c+0, kb)] = pack4(f0.x, f1.x, f2.x, f3.x);
                *(ushort4*)&Rs[sw128(c+1, kb)] = pack4(f0.y, f1.y, f2.y, f3.y);
                *(ushort4*)&Rs[sw128(c+2, kb)] = pack4(f0.z, f1.z, f2.z, f3.z);
                *(ushort4*)&Rs[sw128(c+3, kb)] = pack4(f0.w, f1.w, f2.w, f3.w);
            }
        }
        if (t < 512) stats[t] = 0.f;
    } else {
        {
            int c = lane * 4;  int k4 = wv * 4;
            #pragma unroll
            for (int rep = 0; rep < 4; ++rep) {
                int kb = rep*32 + k4;
                float4 f0 = *(const float4*)(twf + (size_t)(kb+0)*256 + c);
                float4 f1 = *(const float4*)(twf + (size_t)(kb+1)*256 + c);
                float4 f2 = *(const float4*)(twf + (size_t)(kb+2)*256 + c);
                float4 f3 = *(const float4*)(twf + (size_t)(kb+3)*256 + c);
                *(ushort4*)&Ls[sw128(c+0, kb)] = pack4(f0.x, f1.x, f2.x, f3.x);
                *(ushort4*)&Ls[sw128(c+1, kb)] = pack4(f0.y, f1.y, f2.y, f3.y);
                *(ushort4*)&Ls[sw128(c+2, kb)] = pack4(f0.z, f1.z, f2.z, f3.z);
                *(ushort4*)&Ls[sw128(c+3, kb)] = pack4(f0.w, f1.w, f2.w, f3.w);
                float4 g0 = *(const float4*)(pwf + (size_t)(kb+0)*256 + c);
                float4 g1 = *(const float4*)(pwf + (size_t)(kb+1)*256 + c);
                float4 g2 = *(const float4*)(pwf + (size_t)(kb+2)*256 + c);
                float4 g3 = *(const float4*)(pwf + (size_t)(kb+3)*256 + c);
                *(ushort4*)&Rs[sw128(c+0, kb)] = pack4(g0.x, g1.x, g2.x, g3.x);
                *(ushort4*)&Rs[sw128(c+1, kb)] = pack4(g0.y, g1.y, g2.y, g3.y);
                *(ushort4*)&Rs[sw128(c+2, kb)] = pack4(g0.z, g1.z, g2.z, g3.z);
                *(ushort4*)&Rs[sw128(c+3, kb)] = pack4(g0.w, g1.w, g2.w, g3.w);
            }
        }
    }
    __syncthreads();

    int wr = wv >> 2, wc = wv & 3;      // 2x4: tile 128 x 64
    f32x4 acc[8][4];
    #pragma unroll
    for (int i = 0; i < 8; ++i)
        #pragma unroll
        for (int j = 0; j < 4; ++j) acc[i][j] = (f32x4){0.f,0.f,0.f,0.f};
    #pragma unroll
    for (int ks = 0; ks < 4; ++ks) {
        bf16x8 af[8], bfr[4];
        #pragma unroll
        for (int mi = 0; mi < 8; ++mi) {
            int r = wr*128 + mi*16 + lr;
            af[mi] = __builtin_bit_cast(bf16x8, *(const u16x8*)&Ls[sw128(r, ks*32 + lg*8)]);
        }
        #pragma unroll
        for (int ni = 0; ni < 4; ++ni) {
            int c = wc*64 + ni*16 + lr;
            bfr[ni] = __builtin_bit_cast(bf16x8, *(const u16x8*)&Rs[sw128(c, ks*32 + lg*8)]);
        }
        #pragma unroll
        for (int mi = 0; mi < 8; ++mi)
            #pragma unroll
            for (int ni = 0; ni < 4; ++ni)
                acc[mi][ni] = MFMA(af[mi], bfr[ni], acc[mi][ni]);
    }
    unsigned short* Dst = (bid == 136) ? Abf : CmT;
    #pragma unroll
    for (int mi = 0; mi < 8; ++mi)
        #pragma unroll
        for (int ni = 0; ni < 4; ++ni)
            #pragma unroll
            for (int j = 0; j < 4; ++j) {
                int r = wr*128 + mi*16 + lg*4 + j;
                int c = wc*64 + ni*16 + lr;
                Dst[r*256 + c] = f2bf(acc[mi][ni][j]);
            }

    if (bid == 136) {
        if (t < 256) {
            float s = 0.f;
            #pragma unroll
            for (int q = 0; q < 32; ++q) {
                float4 f = *(const float4*)(Wwf + (size_t)t*128 + q*4);
                s += f.x*gbv[q*4] + f.y*gbv[q*4+1] + f.z*gbv[q*4+2] + f.w*gbv[q*4+3];
            }
            a1[t] = s;
        }
    } else {
        if (t < 256) {
            float s1 = 0.f, s2 = 0.f;
            for (int k = 0; k < 128; ++k) {
                s1 += twf[(size_t)k*256 + t] * pbv[k];
                s2 += pwf[(size_t)k*256 + t] * tbv[k];
            }
            c1v[t] = s1; p2[t] = s2;
        }
        if (t < 64) {
            float v = pbv[t]*tbv[t] + pbv[t+64]*tbv[t+64];
            #pragma unroll
            for (int off = 1; off < 64; off <<= 1) v += __shfl_xor(v, off);
            if (t == 0) params[0] = v;
        }
    }
}

// ============ kE: 32 blocks (b, o-slice of 64). Y=A_sl*S; E=(Y*Cm)/N + rank-2; f; BN stats ============
__global__ __launch_bounds__(512) void kE(
    const unsigned short* __restrict__ Sbf, const float* __restrict__ rv,
    const unsigned short* __restrict__ Abf, const unsigned short* __restrict__ CmT,
    const float* __restrict__ a1g, const float* __restrict__ c1vg, const float* __restrict__ p2g,
    const float* __restrict__ params, const float* __restrict__ Wbv,
    unsigned short* __restrict__ Ebf, float* __restrict__ fv, float* __restrict__ stats)
{
    __shared__ __align__(16) unsigned short Ybuf[16384];
    __shared__ __align__(16) unsigned short Ebuf[16384];
    __shared__ float r_l[256], p2_l[256], c1v_l[256], cr[256];
    __shared__ float a1_l[64], ar[64], Yp2[64], er[64], diag_l[64];
    __shared__ float rp2_s;
    int blk = blockIdx.x;
    int b = blk >> 2, obase = (blk & 3) * 64;
    int t = threadIdx.x, lane = t & 63, wv = t >> 6;
    int lr = lane & 15, lg = lane >> 4;
    const float invN = 1.0f/4096.0f;
    const unsigned short* Sb = Sbf + (size_t)b*65536;

    if (t < 256) {
        r_l[t] = rv[b*256 + t];
        p2_l[t] = p2g[t];
        c1v_l[t] = c1vg[t];
    } else if (t < 320) {
        a1_l[t - 256] = a1g[obase + (t - 256)];
    }
    __syncthreads();

    f32x4 acc[4][2];
    #pragma unroll
    for (int i = 0; i < 4; ++i) { acc[i][0] = (f32x4){0,0,0,0}; acc[i][1] = (f32x4){0,0,0,0}; }
    const unsigned short* Arow0 = Abf + (size_t)obase*256;
    #pragma unroll
    for (int ks = 0; ks < 8; ++ks) {
        bf16x8 a4[4], b2[2];
        #pragma unroll
        for (int mi = 0; mi < 4; ++mi)
            a4[mi] = __builtin_bit_cast(bf16x8, *(const u16x8*)(Arow0 + (size_t)(mi*16+lr)*256 + ks*32 + lg*8));
        #pragma unroll
        for (int ni = 0; ni < 2; ++ni)
            b2[ni] = __builtin_bit_cast(bf16x8, *(const u16x8*)(Sb + (size_t)(wv*32+ni*16+lr)*256 + ks*32 + lg*8));
        #pragma unroll
        for (int mi = 0; mi < 4; ++mi)
            #pragma unroll
            for (int ni = 0; ni < 2; ++ni)
                acc[mi][ni] = MFMA(a4[mi], b2[ni], acc[mi][ni]);
    }
    #pragma unroll
    for (int mi = 0; mi < 4; ++mi)
        #pragma unroll
        for (int ni = 0; ni < 2; ++ni)
            #pragma unroll
            for (int j = 0; j < 4; ++j) {
                int ol = mi*16 + lg*4 + j;
                int c2 = wv*32 + ni*16 + lr;
                Ybuf[ol*256 + (c2 ^ ((ol&7)<<3))] = f2bf(acc[mi][ni][j]);
            }
    __syncthreads();

    {
        int row = t >> 3, p8 = t & 7;
        float sA = 0.f, sY = 0.f;
        const unsigned short* Ar = Abf + (size_t)(obase + row)*256 + p8*32;
        #pragma unroll
        for (int q = 0; q < 4; ++q) {
            u16x8 av = *(const u16x8*)(Ar + q*8);
            #pragma unroll
            for (int e = 0; e < 8; ++e) {
                int c = p8*32 + q*8 + e;
                sA += bf2f(av[e]) * r_l[c];
                sY += bf2f(Ybuf[row*256 + (c ^ ((row&7)<<3))]) * p2_l[c];
            }
        }
        sA += __shfl_xor(sA, 1); sA += __shfl_xor(sA, 2); sA += __shfl_xor(sA, 4);
        sY += __shfl_xor(sY, 1); sY += __shfl_xor(sY, 2); sY += __shfl_xor(sY, 4);
        if (p8 == 0) { ar[row] = sA; Yp2[row] = sY; }
    }
    if (t < 256) {
        float s = 0.f;
        const unsigned short* Cr = CmT + (size_t)t*256;
        #pragma unroll
        for (int q = 0; q < 32; ++q) {
            u16x8 v = *(const u16x8*)(Cr + q*8);
            #pragma unroll
            for (int e = 0; e < 8; ++e) s += bf2f(v[e]) * r_l[q*8 + e];
        }
        cr[t] = s;
    }
    if (t < 64) {
        float v = r_l[t*4]*p2_l[t*4] + r_l[t*4+1]*p2_l[t*4+1]
                + r_l[t*4+2]*p2_l[t*4+2] + r_l[t*4+3]*p2_l[t*4+3];
        #pragma unroll
        for (int off = 1; off < 64; off <<= 1) v += __shfl_xor(v, off);
        if (t == 0) rp2_s = v;
    }
    __syncthreads();

    f32x4 accE[4][2];
    #pragma unroll
    for (int i = 0; i < 4; ++i) { accE[i][0] = (f32x4){0,0,0,0}; accE[i][1] = (f32x4){0,0,0,0}; }
    #pragma unroll
    for (int ks = 0; ks < 8; ++ks) {
        bf16x8 a4[4], b2[2];
        #pragma unroll
        for (int mi = 0; mi < 4; ++mi) {
            int ol = mi*16 + lr;
            a4[mi] = __builtin_bit_cast(bf16x8, *(const u16x8*)&Ybuf[ol*256 + ((ks*32 + lg*8) ^ ((ol&7)<<3))]);
        }
        #pragma unroll
        for (int ni = 0; ni < 2; ++ni)
            b2[ni] = __builtin_bit_cast(bf16x8, *(const u16x8*)(CmT + (size_t)(wv*32+ni*16+lr)*256 + ks*32 + lg*8));
        #pragma unroll
        for (int mi = 0; mi < 4; ++mi)
            #pragma unroll
            for (int ni = 0; ni < 2; ++ni)
                accE[mi][ni] = MFMA(a4[mi], b2[ni], accE[mi][ni]);
    }
    unsigned short* Eb = Ebf + (size_t)b*65536;
    #pragma unroll
    for (int mi = 0; mi < 4; ++mi)
        #pragma unroll
        for (int ni = 0; ni < 2; ++ni)
            #pragma unroll
            for (int j = 0; j < 4; ++j) {
                int ol = mi*16 + lg*4 + j;
                int cp = wv*32 + ni*16 + lr;
                float e = accE[mi][ni][j]*invN + a1_l[ol]*invN*cr[cp]
                        + (invN*ar[ol] + a1_l[ol])*c1v_l[cp];
                unsigned short eb = f2bf(e);
                Ebuf[ol*256 + (cp ^ ((ol&7)<<3))] = eb;
                Eb[(size_t)(obase + ol)*256 + cp] = eb;
            }
    __syncthreads();

    float f_reg = 0.f;
    {
        int row = t >> 3, p8 = t & 7;
        float s = 0.f;
        #pragma unroll
        for (int q = 0; q < 4; ++q)
            #pragma unroll
            for (int e = 0; e < 8; ++e) {
                int c = p8*32 + q*8 + e;
                s += bf2f(Ebuf[row*256 + (c ^ ((row&7)<<3))]) * r_l[c];
            }
        s += __shfl_xor(s, 1); s += __shfl_xor(s, 2); s += __shfl_xor(s, 4);
        if (p8 == 0) er[row] = s;
    }
    if (t < 64) {
        diag_l[t] = 0.f;
        float sg = params[0];
        f_reg = invN*(Yp2[t] + a1_l[t]*rp2_s + ar[t]*sg) + a1_l[t]*sg + Wbv[obase + t];
        fv[b*256 + obase + t] = f_reg;
    }
    __syncthreads();

    f32x4 accZ[4][2];
    #pragma unroll
    for (int i = 0; i < 4; ++i) { accZ[i][0] = (f32x4){0,0,0,0}; accZ[i][1] = (f32x4){0,0,0,0}; }
    #pragma unroll
    for (int ks = 0; ks < 8; ++ks) {
        bf16x8 a4[4], b2[2];
        #pragma unroll
        for (int mi = 0; mi < 4; ++mi) {
            int ol = mi*16 + lr;
            a4[mi] = __builtin_bit_cast(bf16x8, *(const u16x8*)&Ebuf[ol*256 + ((ks*32 + lg*8) ^ ((ol&7)<<3))]);
        }
        #pragma unroll
        for (int ni = 0; ni < 2; ++ni)
            b2[ni] = __builtin_bit_cast(bf16x8, *(const u16x8*)(Sb + (size_t)(wv*32+ni*16+lr)*256 + ks*32 + lg*8));
        #pragma unroll
        for (int mi = 0; mi < 4; ++mi)
            #pragma unroll
            for (int ni = 0; ni < 2; ++ni)
                accZ[mi][ni] = MFMA(a4[mi], b2[ni], accZ[mi][ni]);
    }
    #pragma unroll
    for (int mi = 0; mi < 4; ++mi)
        #pragma unroll
        for (int j = 0; j < 4; ++j) {
            int ol = mi*16 + lg*4 + j;
            float s = 0.f;
            #pragma unroll
            for (int ni = 0; ni < 2; ++ni) {
                int c2 = wv*32 + ni*16 + lr;
                s += accZ[mi][ni][j] * bf2f(Ebuf[ol*256 + (c2 ^ ((ol&7)<<3))]);
            }
            s += __shfl_xor(s, 1); s += __shfl_xor(s, 2);
            s += __shfl_xor(s, 4); s += __shfl_xor(s, 8);
            if (lr == 0) atomicAdd(&diag_l[ol], s);
        }
    __syncthreads();

    if (t < 64) {
        int o = obase + t;
        atomicAdd(&stats[o], er[t] + 4096.0f*f_reg);
        atomicAdd(&stats[256 + o], diag_l[t] + 2.0f*f_reg*er[t] + 4096.0f*f_reg*f_reg);
    }
}

// ============ kF: 512 blocks (b, 64-n tile). out = (E x + f - mu)*sc + beta + x ============
__global__ __launch_bounds__(512) void kF(
    const float* __restrict__ x, const unsigned short* __restrict__ Ebf,
    const float* __restrict__ fv, const float* __restrict__ stats,
    const float* __restrict__ gamma, const float* __restrict__ beta,
    float* __restrict__ out)
{
    __shared__ __align__(16) unsigned short Xs[64*256];   // 32 KB, [n][c] swz
    __shared__ float scale_l[256], shift_l[256];
    int b = blockIdx.x >> 6, n0 = (blockIdx.x & 63) * 64;
    int t = threadIdx.x, lane = t & 63, wv = t >> 6, lr = lane & 15, lg = lane >> 4;
    const float inv = 1.0f / 32768.0f;
    if (t < 256) {
        float mu  = stats[t] * inv;
        float var = stats[256 + t] * inv - mu*mu;
        float sc  = gamma[t] * rsqrtf(var + 1e-5f);
        scale_l[t] = sc;
        shift_l[t] = (fv[b*256 + t] - mu) * sc + beta[t];
    }
    {
        int n4 = (t & 15) * 4;            // 0..60
        int cb = (t >> 4) * 4;            // 0..124
        const float* xb = x + (size_t)b*CIN*NN + n0 + n4;
        float4 f[8];
        #pragma unroll
        for (int p = 0; p < 2; ++p) {
            int c = p*128 + cb;
            const float* xp = xb + (size_t)c*NN;
            f[p*4+0] = *(const float4*)(xp);
            f[p*4+1] = *(const float4*)(xp + NN);
            f[p*4+2] = *(const float4*)(xp + 2*NN);
            f[p*4+3] = *(const float4*)(xp + 3*NN);
        }
        #pragma unroll
        for (int p = 0; p < 2; ++p) {
            int c = p*128 + cb;
            *(ushort4*)&Xs[(n4+0)*256 + (c ^ (((n4+0)&7)<<3))] = pack4(f[p*4].x, f[p*4+1].x, f[p*4+2].x, f[p*4+3].x);
            *(ushort4*)&Xs[(n4+1)*256 + (c ^ (((n4+1)&7)<<3))] = pack4(f[p*4].y, f[p*4+1].y, f[p*4+2].y, f[p*4+3].y);
            *(ushort4*)&Xs[(n4+2)*256 + (c ^ (((n4+2)&7)<<3))] = pack4(f[p*4].z, f[p*4+1].z, f[p*4+2].z, f[p*4+3].z);
            *(ushort4*)&Xs[(n4+3)*256 + (c ^ (((n4+3)&7)<<3))] = pack4(f[p*4].w, f[p*4+1].w, f[p*4+2].w, f[p*4+3].w);
        }
    }
    __syncthreads();

    int wn = wv >> 2, wo = wv & 3;        // 2n x 4o
    int nb = wn*32, ob = wo*64;
    const unsigned short* Eb = Ebf + (size_t)b*65536;
    f32x4 acc[4][2];                      // [oi][ni]
    #pragma unroll
    for (int i = 0; i < 4; ++i) { acc[i][0] = (f32x4){0,0,0,0}; acc[i][1] = (f32x4){0,0,0,0}; }

    #pragma unroll
    for (int ks = 0; ks < 8; ++ks) {
        bf16x8 xf[2], ef[4];
        #pragma unroll
        for (int ni = 0; ni < 2; ++ni) {
            int n = nb + ni*16 + lr;
            xf[ni] = __builtin_bit_cast(bf16x8, *(const u16x8*)&Xs[(n*256 + ks*32 + lg*8) ^ ((n&7)<<3)]);
        }
        #pragma unroll
        for (int oi = 0; oi < 4; ++oi) {
            int o = ob + oi*16 + lr;
            ef[oi] = __builtin_bit_cast(bf16x8, *(const u16x8*)(Eb + (size_t)o*256 + ks*32 + lg*8));
        }
        #pragma unroll
        for (int oi = 0; oi < 4; ++oi)
            #pragma unroll
            for (int ni = 0; ni < 2; ++ni)
                acc[oi][ni] = MFMA(ef[oi], xf[ni], acc[oi][ni]);
    }

    float* op = out + (size_t)b*CIN*NN + n0;
    #pragma unroll
    for (int oi = 0; oi < 4; ++oi) {
        #pragma unroll
        for (int j = 0; j < 4; ++j) {
            int o = ob + oi*16 + lg*4 + j;
            float sc = scale_l[o], sh = shift_l[o];
            #pragma unroll
            for (int ni = 0; ni < 2; ++ni) {
                int n = nb + ni*16 + lr;
                float val = acc[oi][ni][j]*sc + sh + bf2f(Xs[(n*256 + (o ^ ((n&7)<<3)))]);
                op[(size_t)o*NN + n] = val;
            }
        }
    }
}

extern "C" void kernel_launch(void* const* d_in, const int* in_sizes, int n_in,
                              void* d_out, int out_size, void* d_ws, size_t ws_size,
                              hipStream_t stream)
{
    (void)in_sizes; (void)n_in; (void)out_size; (void)ws_size;
    const float* x     = (const float*)d_in[0];
    const float* gw    = (const float*)d_in[1];
    const float* gb    = (const float*)d_in[2];
    const float* tw    = (const float*)d_in[3];
    const float* tb    = (const float*)d_in[4];
    const float* pw    = (const float*)d_in[5];
    const float* pb    = (const float*)d_in[6];
    const float* Ww    = (const float*)d_in[7];
    const float* Wb    = (const float*)d_in[8];
    const float* gamma = (const float*)d_in[9];
    const float* beta  = (const float*)d_in[10];
    float* out = (float*)d_out;

    char* ws = (char*)d_ws;
    unsigned short* Sp  = (unsigned short*)(ws + 0);          // 32 MB (256 partials x 128KB)
    float* Rp           = (float*)(ws + 33554432);            // 256 KB
    unsigned short* Sbf = (unsigned short*)(ws + 33816576);   // 1 MB
    float* rv           = (float*)(ws + 34865152);            // 8 KB
    unsigned short* Abf = (unsigned short*)(ws + 34873344);   // 128 KB
    unsigned short* CmT = (unsigned short*)(ws + 35004416);   // 128 KB
    unsigned short* Ebf = (unsigned short*)(ws + 35135488);   // 1 MB
    float* fv           = (float*)(ws + 36184064);            // 8 KB
    float* a1           = (float*)(ws + 36192256);            // 1 KB
    float* c1v          = (float*)(ws + 36193280);            // 1 KB
    float* p2           = (float*)(ws + 36194304);            // 1 KB
    float* params       = (float*)(ws + 36195328);            // 64 B
    float* stats        = (float*)(ws + 36195392);            // 2 KB

    kA<<<256, 512, 0, stream>>>(x, Sp, Rp);
    kR<<<138, 512, 0, stream>>>(Sp, Rp, Ww, gw, tw, pw, gb, pb, tb,
                                Sbf, rv, Abf, CmT, a1, c1v, p2, params, stats);
    kE<<<32,  512, 0, stream>>>(Sbf, rv, Abf, CmT, a1, c1v, p2, params, Wb, Ebf, fv, stats);
    kF<<<512, 512, 0, stream>>>(x, Ebf, fv, stats, gamma, beta, out);
}

// Round 12
// 82.631 us; speedup vs baseline: 1.2209x; 1.2209x over previous
//
#include <hip/hip_runtime.h>
#include <hip/hip_bf16.h>
#include <stdint.h>

#define BB   8
#define CIN  256
#define COUT 128
#define NN   4096

using f32x4  = __attribute__((ext_vector_type(4))) float;
using bf16x8 = __attribute__((ext_vector_type(8))) __bf16;
using u16x8  = __attribute__((ext_vector_type(8))) unsigned short;

static __device__ __forceinline__ unsigned short f2bf(float f) {
    unsigned int u = __builtin_bit_cast(unsigned int, f);
    u += 0x7FFFu + ((u >> 16) & 1u);
    return (unsigned short)(u >> 16);
}
static __device__ __forceinline__ float bf2f(unsigned short u) {
    return __builtin_bit_cast(float, (unsigned int)u << 16);
}
static __device__ __forceinline__ ushort4 pack4(float a, float b, float c, float d) {
    ushort4 r; r.x=f2bf(a); r.y=f2bf(b); r.z=f2bf(c); r.w=f2bf(d); return r;
}
#define MFMA(a,b,c) __builtin_amdgcn_mfma_f32_16x16x32_bf16((a),(b),(c),0,0,0)

static __device__ __forceinline__ int sw256(int r, int c) { return (r*256 + c) ^ ((r&7)<<3); }
static __device__ __forceinline__ int sw128(int r, int c) { return (r*128 + c) ^ ((r&7)<<3); }

// ============ kA: 130 blocks x 512 (r9 shape).
//   0-127: Gram partials Sp[bid] (bf16) + Rp + bf16 x copy Xbf[b][c][n]
//   128  : Abf = Ww*Gw, a1 = Ww*gb, zero stats
//   129  : CmT = Tw^T*Pw, c1v = Tw^T*pb, p2 = Pw^T*tb, sigma ============
__global__ __launch_bounds__(512) void kA(
    const float* __restrict__ x,
    const float* __restrict__ Wwf, const float* __restrict__ gwf,
    const float* __restrict__ twf, const float* __restrict__ pwf,
    const float* __restrict__ gbv, const float* __restrict__ pbv, const float* __restrict__ tbv,
    unsigned short* __restrict__ Sp, float* __restrict__ Rp,
    unsigned short* __restrict__ Xbf,
    unsigned short* __restrict__ Abf, unsigned short* __restrict__ CmT,
    float* __restrict__ a1, float* __restrict__ c1v, float* __restrict__ p2,
    float* __restrict__ params, float* __restrict__ stats)
{
    __shared__ __align__(16) unsigned short SH[65536];   // 128 KB
    int bid = blockIdx.x;
    int t = threadIdx.x, lane = t & 63, wv = t >> 6;
    int lr = lane & 15, lg = lane >> 4;

    if (bid < 128) {
        int b = bid >> 4, ch = bid & 15;
        int n0 = ch * 256;
        const float* xb = x + (size_t)b*CIN*NN + n0 + lane*4;
        unsigned short* xtb = Xbf + (size_t)b*CIN*NN + n0 + lane*4;
        // two-phase staging: 16 loads in flight, then convert + write LDS + write Xbf
        #pragma unroll
        for (int g = 0; g < 2; ++g) {
            float4 v[16];
            #pragma unroll
            for (int i = 0; i < 16; ++i) {
                int c = wv*32 + g*16 + i;
                v[i] = *(const float4*)(xb + (size_t)c*NN);
            }
            #pragma unroll
            for (int i = 0; i < 16; ++i) {
                int c = wv*32 + g*16 + i;
                ushort4 pk = pack4(v[i].x, v[i].y, v[i].z, v[i].w);
                *(ushort4*)&SH[sw256(c, lane*4)] = pk;
                *(ushort4*)(xtb + (size_t)c*NN) = pk;
            }
        }
        __syncthreads();

        int wr = wv >> 1, wc = wv & 1;      // 4x2: tile 64 x 128
        f32x4 acc[4][8];
        #pragma unroll
        for (int i = 0; i < 4; ++i)
            #pragma unroll
            for (int j = 0; j < 8; ++j) acc[i][j] = (f32x4){0.f,0.f,0.f,0.f};
        #pragma unroll
        for (int ks = 0; ks < 8; ++ks) {
            bf16x8 af[4], bfr[8];
            #pragma unroll
            for (int mi = 0; mi < 4; ++mi) {
                int row = wr*64 + mi*16 + lr;
                af[mi] = __builtin_bit_cast(bf16x8, *(const u16x8*)&SH[sw256(row, ks*32 + lg*8)]);
            }
            #pragma unroll
            for (int ni = 0; ni < 8; ++ni) {
                int row = wc*128 + ni*16 + lr;
                bfr[ni] = __builtin_bit_cast(bf16x8, *(const u16x8*)&SH[sw256(row, ks*32 + lg*8)]);
            }
            #pragma unroll
            for (int mi = 0; mi < 4; ++mi)
                #pragma unroll
                for (int ni = 0; ni < 8; ++ni)
                    acc[mi][ni] = MFMA(af[mi], bfr[ni], acc[mi][ni]);
        }
        // row-sums from staged LDS (off the load critical path)
        if (t < 256) {
            float s = 0.f;
            #pragma unroll
            for (int q = 0; q < 32; ++q) {
                u16x8 vv = *(const u16x8*)&SH[sw256(t, q*8)];
                #pragma unroll
                for (int e = 0; e < 8; ++e) s += bf2f(vv[e]);
            }
            Rp[bid*256 + t] = s;
        }
        __syncthreads();   // all SH reads complete before overwrite
        // dump acc -> SH (swizzled)
        #pragma unroll
        for (int mi = 0; mi < 4; ++mi)
            #pragma unroll
            for (int ni = 0; ni < 8; ++ni)
                #pragma unroll
                for (int j = 0; j < 4; ++j) {
                    int c1 = wr*64 + mi*16 + lg*4 + j;
                    int c2 = wc*128 + ni*16 + lr;
                    SH[sw256(c1, c2)] = f2bf(acc[mi][ni][j]);
                }
        __syncthreads();
        // coalesced u16x8 store: 512B contiguous per row
        unsigned short* dst = Sp + (size_t)bid * 65536;
        #pragma unroll
        for (int i = t; i < 8192; i += 512) {
            int row = i >> 5, q = i & 31;
            *(u16x8*)(dst + row*256 + ((q ^ (row&7)) * 8)) = *(const u16x8*)&SH[row*256 + q*8];
        }
        return;
    }

    // ---- weight precompute blocks ----
    unsigned short* Ls = SH;
    unsigned short* Rs = SH + 32768;
    if (bid == 128) {
        for (int i = t; i < 8192; i += 512) {
            int flat = i*4, r = flat >> 7, c = flat & 127;
            float4 f = *(const float4*)(Wwf + flat);
            *(ushort4*)&Ls[sw128(r, c)] = pack4(f.x, f.y, f.z, f.w);
        }
        {
            int c = lane * 4;  int k4 = wv * 4;
            #pragma unroll
            for (int rep = 0; rep < 4; ++rep) {
                int kb = rep*32 + k4;
                float4 f0 = *(const float4*)(gwf + (size_t)(kb+0)*256 + c);
                float4 f1 = *(const float4*)(gwf + (size_t)(kb+1)*256 + c);
                float4 f2 = *(const float4*)(gwf + (size_t)(kb+2)*256 + c);
                float4 f3 = *(const float4*)(gwf + (size_t)(kb+3)*256 + c);
                *(ushort4*)&Rs[sw128(c+0, kb)] = pack4(f0.x, f1.x, f2.x, f3.x);
                *(ushort4*)&Rs[sw128(c+1, kb)] = pack4(f0.y, f1.y, f2.y, f3.y);
                *(ushort4*)&Rs[sw128(c+2, kb)] = pack4(f0.z, f1.z, f2.z, f3.z);
                *(ushort4*)&Rs[sw128(c+3, kb)] = pack4(f0.w, f1.w, f2.w, f3.w);
            }
        }
        if (t < 512) stats[t] = 0.f;
    } else {
        {
            int c = lane * 4;  int k4 = wv * 4;
            #pragma unroll
            for (int rep = 0; rep < 4; ++rep) {
                int kb = rep*32 + k4;
                float4 f0 = *(const float4*)(twf + (size_t)(kb+0)*256 + c);
                float4 f1 = *(const float4*)(twf + (size_t)(kb+1)*256 + c);
                float4 f2 = *(const float4*)(twf + (size_t)(kb+2)*256 + c);
                float4 f3 = *(const float4*)(twf + (size_t)(kb+3)*256 + c);
                *(ushort4*)&Ls[sw128(c+0, kb)] = pack4(f0.x, f1.x, f2.x, f3.x);
                *(ushort4*)&Ls[sw128(c+1, kb)] = pack4(f0.y, f1.y, f2.y, f3.y);
                *(ushort4*)&Ls[sw128(c+2, kb)] = pack4(f0.z, f1.z, f2.z, f3.z);
                *(ushort4*)&Ls[sw128(c+3, kb)] = pack4(f0.w, f1.w, f2.w, f3.w);
                float4 g0 = *(const float4*)(pwf + (size_t)(kb+0)*256 + c);
                float4 g1 = *(const float4*)(pwf + (size_t)(kb+1)*256 + c);
                float4 g2 = *(const float4*)(pwf + (size_t)(kb+2)*256 + c);
                float4 g3 = *(const float4*)(pwf + (size_t)(kb+3)*256 + c);
                *(ushort4*)&Rs[sw128(c+0, kb)] = pack4(g0.x, g1.x, g2.x, g3.x);
                *(ushort4*)&Rs[sw128(c+1, kb)] = pack4(g0.y, g1.y, g2.y, g3.y);
                *(ushort4*)&Rs[sw128(c+2, kb)] = pack4(g0.z, g1.z, g2.z, g3.z);
                *(ushort4*)&Rs[sw128(c+3, kb)] = pack4(g0.w, g1.w, g2.w, g3.w);
            }
        }
    }
    __syncthreads();

    int wr = wv >> 2, wc = wv & 3;      // 2x4: tile 128 x 64
    f32x4 acc[8][4];
    #pragma unroll
    for (int i = 0; i < 8; ++i)
        #pragma unroll
        for (int j = 0; j < 4; ++j) acc[i][j] = (f32x4){0.f,0.f,0.f,0.f};
    #pragma unroll
    for (int ks = 0; ks < 4; ++ks) {
        bf16x8 af[8], bfr[4];
        #pragma unroll
        for (int mi = 0; mi < 8; ++mi) {
            int r = wr*128 + mi*16 + lr;
            af[mi] = __builtin_bit_cast(bf16x8, *(const u16x8*)&Ls[sw128(r, ks*32 + lg*8)]);
        }
        #pragma unroll
        for (int ni = 0; ni < 4; ++ni) {
            int c = wc*64 + ni*16 + lr;
            bfr[ni] = __builtin_bit_cast(bf16x8, *(const u16x8*)&Rs[sw128(c, ks*32 + lg*8)]);
        }
        #pragma unroll
        for (int mi = 0; mi < 8; ++mi)
            #pragma unroll
            for (int ni = 0; ni < 4; ++ni)
                acc[mi][ni] = MFMA(af[mi], bfr[ni], acc[mi][ni]);
    }
    unsigned short* Dst = (bid == 128) ? Abf : CmT;
    #pragma unroll
    for (int mi = 0; mi < 8; ++mi)
        #pragma unroll
        for (int ni = 0; ni < 4; ++ni)
            #pragma unroll
            for (int j = 0; j < 4; ++j) {
                int r = wr*128 + mi*16 + lg*4 + j;
                int c = wc*64 + ni*16 + lr;
                Dst[r*256 + c] = f2bf(acc[mi][ni][j]);
            }

    if (bid == 128) {
        if (t < 256) {
            float s = 0.f;
            #pragma unroll
            for (int q = 0; q < 32; ++q) {
                float4 f = *(const float4*)(Wwf + (size_t)t*128 + q*4);
                s += f.x*gbv[q*4] + f.y*gbv[q*4+1] + f.z*gbv[q*4+2] + f.w*gbv[q*4+3];
            }
            a1[t] = s;
        }
    } else {
        if (t < 256) {
            float s1 = 0.f, s2 = 0.f;
            for (int k = 0; k < 128; ++k) {
                s1 += twf[(size_t)k*256 + t] * pbv[k];
                s2 += pwf[(size_t)k*256 + t] * tbv[k];
            }
            c1v[t] = s1; p2[t] = s2;
        }
        if (t < 64) {
            float v = pbv[t]*tbv[t] + pbv[t+64]*tbv[t+64];
            #pragma unroll
            for (int off = 1; off < 64; off <<= 1) v += __shfl_xor(v, off);
            if (t == 0) params[0] = v;
        }
    }
}

// ============ kR: 136 blocks. 0-127: Sbf[b] = sum 16 partials; 128-135: rv ============
__global__ __launch_bounds__(512) void kR(
    const unsigned short* __restrict__ Sp, const float* __restrict__ Rp,
    unsigned short* __restrict__ Sbf, float* __restrict__ rv)
{
    int bid = blockIdx.x, t = threadIdx.x;
    if (bid < 128) {
        int b = bid >> 4, sl = bid & 15;
        int base = sl*4096 + t*8;
        float s[8] = {0.f,0.f,0.f,0.f,0.f,0.f,0.f,0.f};
        #pragma unroll
        for (int i = 0; i < 16; ++i) {
            u16x8 v = *(const u16x8*)(Sp + (size_t)(b*16 + i)*65536 + base);
            #pragma unroll
            for (int e = 0; e < 8; ++e) s[e] += bf2f(v[e]);
        }
        u16x8 o;
        #pragma unroll
        for (int e = 0; e < 8; ++e) o[e] = f2bf(s[e]);
        *(u16x8*)(Sbf + (size_t)b*65536 + base) = o;
    } else {
        int b = bid - 128;
        if (t < 256) {
            float s = 0.f;
            #pragma unroll
            for (int i = 0; i < 16; ++i) s += Rp[(b*16 + i)*256 + t];
            rv[b*256 + t] = s;
        }
    }
}

// ============ kE: 32 blocks (b, o-slice of 64). Y=A_sl*S; E=(Y*Cm)/N + rank-2; f; BN stats ============
__global__ __launch_bounds__(512) void kE(
    const unsigned short* __restrict__ Sbf, const float* __restrict__ rv,
    const unsigned short* __restrict__ Abf, const unsigned short* __restrict__ CmT,
    const float* __restrict__ a1g, const float* __restrict__ c1vg, const float* __restrict__ p2g,
    const float* __restrict__ params, const float* __restrict__ Wbv,
    unsigned short* __restrict__ Ebf, float* __restrict__ fv, float* __restrict__ stats)
{
    __shared__ __align__(16) unsigned short Ybuf[16384];
    __shared__ __align__(16) unsigned short Ebuf[16384];
    __shared__ float r_l[256], p2_l[256], c1v_l[256], cr[256];
    __shared__ float a1_l[64], ar[64], Yp2[64], er[64], diag_l[64];
    __shared__ float rp2_s;
    int blk = blockIdx.x;
    int b = blk >> 2, obase = (blk & 3) * 64;
    int t = threadIdx.x, lane = t & 63, wv = t >> 6;
    int lr = lane & 15, lg = lane >> 4;
    const float invN = 1.0f/4096.0f;
    const unsigned short* Sb = Sbf + (size_t)b*65536;

    if (t < 256) {
        r_l[t] = rv[b*256 + t];
        p2_l[t] = p2g[t];
        c1v_l[t] = c1vg[t];
    } else if (t < 320) {
        a1_l[t - 256] = a1g[obase + (t - 256)];
    }
    __syncthreads();

    f32x4 acc[4][2];
    #pragma unroll
    for (int i = 0; i < 4; ++i) { acc[i][0] = (f32x4){0,0,0,0}; acc[i][1] = (f32x4){0,0,0,0}; }
    const unsigned short* Arow0 = Abf + (size_t)obase*256;
    #pragma unroll
    for (int ks = 0; ks < 8; ++ks) {
        bf16x8 a4[4], b2[2];
        #pragma unroll
        for (int mi = 0; mi < 4; ++mi)
            a4[mi] = __builtin_bit_cast(bf16x8, *(const u16x8*)(Arow0 + (size_t)(mi*16+lr)*256 + ks*32 + lg*8));
        #pragma unroll
        for (int ni = 0; ni < 2; ++ni)
            b2[ni] = __builtin_bit_cast(bf16x8, *(const u16x8*)(Sb + (size_t)(wv*32+ni*16+lr)*256 + ks*32 + lg*8));
        #pragma unroll
        for (int mi = 0; mi < 4; ++mi)
            #pragma unroll
            for (int ni = 0; ni < 2; ++ni)
                acc[mi][ni] = MFMA(a4[mi], b2[ni], acc[mi][ni]);
    }
    #pragma unroll
    for (int mi = 0; mi < 4; ++mi)
        #pragma unroll
        for (int ni = 0; ni < 2; ++ni)
            #pragma unroll
            for (int j = 0; j < 4; ++j) {
                int ol = mi*16 + lg*4 + j;
                int c2 = wv*32 + ni*16 + lr;
                Ybuf[ol*256 + (c2 ^ ((ol&7)<<3))] = f2bf(acc[mi][ni][j]);
            }
    __syncthreads();

    {
        int row = t >> 3, p8 = t & 7;
        float sA = 0.f, sY = 0.f;
        const unsigned short* Ar = Abf + (size_t)(obase + row)*256 + p8*32;
        #pragma unroll
        for (int q = 0; q < 4; ++q) {
            u16x8 av = *(const u16x8*)(Ar + q*8);
            #pragma unroll
            for (int e = 0; e < 8; ++e) {
                int c = p8*32 + q*8 + e;
                sA += bf2f(av[e]) * r_l[c];
                sY += bf2f(Ybuf[row*256 + (c ^ ((row&7)<<3))]) * p2_l[c];
            }
        }
        sA += __shfl_xor(sA, 1); sA += __shfl_xor(sA, 2); sA += __shfl_xor(sA, 4);
        sY += __shfl_xor(sY, 1); sY += __shfl_xor(sY, 2); sY += __shfl_xor(sY, 4);
        if (p8 == 0) { ar[row] = sA; Yp2[row] = sY; }
    }
    if (t < 256) {
        float s = 0.f;
        const unsigned short* Cr = CmT + (size_t)t*256;
        #pragma unroll
        for (int q = 0; q < 32; ++q) {
            u16x8 v = *(const u16x8*)(Cr + q*8);
            #pragma unroll
            for (int e = 0; e < 8; ++e) s += bf2f(v[e]) * r_l[q*8 + e];
        }
        cr[t] = s;
    }
    if (t < 64) {
        float v = r_l[t*4]*p2_l[t*4] + r_l[t*4+1]*p2_l[t*4+1]
                + r_l[t*4+2]*p2_l[t*4+2] + r_l[t*4+3]*p2_l[t*4+3];
        #pragma unroll
        for (int off = 1; off < 64; off <<= 1) v += __shfl_xor(v, off);
        if (t == 0) rp2_s = v;
    }
    __syncthreads();

    f32x4 accE[4][2];
    #pragma unroll
    for (int i = 0; i < 4; ++i) { accE[i][0] = (f32x4){0,0,0,0}; accE[i][1] = (f32x4){0,0,0,0}; }
    #pragma unroll
    for (int ks = 0; ks < 8; ++ks) {
        bf16x8 a4[4], b2[2];
        #pragma unroll
        for (int mi = 0; mi < 4; ++mi) {
            int ol = mi*16 + lr;
            a4[mi] = __builtin_bit_cast(bf16x8, *(const u16x8*)&Ybuf[ol*256 + ((ks*32 + lg*8) ^ ((ol&7)<<3))]);
        }
        #pragma unroll
        for (int ni = 0; ni < 2; ++ni)
            b2[ni] = __builtin_bit_cast(bf16x8, *(const u16x8*)(CmT + (size_t)(wv*32+ni*16+lr)*256 + ks*32 + lg*8));
        #pragma unroll
        for (int mi = 0; mi < 4; ++mi)
            #pragma unroll
            for (int ni = 0; ni < 2; ++ni)
                accE[mi][ni] = MFMA(a4[mi], b2[ni], accE[mi][ni]);
    }
    unsigned short* Eb = Ebf + (size_t)b*65536;
    #pragma unroll
    for (int mi = 0; mi < 4; ++mi)
        #pragma unroll
        for (int ni = 0; ni < 2; ++ni)
            #pragma unroll
            for (int j = 0; j < 4; ++j) {
                int ol = mi*16 + lg*4 + j;
                int cp = wv*32 + ni*16 + lr;
                float e = accE[mi][ni][j]*invN + a1_l[ol]*invN*cr[cp]
                        + (invN*ar[ol] + a1_l[ol])*c1v_l[cp];
                unsigned short eb = f2bf(e);
                Ebuf[ol*256 + (cp ^ ((ol&7)<<3))] = eb;
                Eb[(size_t)(obase + ol)*256 + cp] = eb;
            }
    __syncthreads();

    float f_reg = 0.f;
    {
        int row = t >> 3, p8 = t & 7;
        float s = 0.f;
        #pragma unroll
        for (int q = 0; q < 4; ++q)
            #pragma unroll
            for (int e = 0; e < 8; ++e) {
                int c = p8*32 + q*8 + e;
                s += bf2f(Ebuf[row*256 + (c ^ ((row&7)<<3))]) * r_l[c];
            }
        s += __shfl_xor(s, 1); s += __shfl_xor(s, 2); s += __shfl_xor(s, 4);
        if (p8 == 0) er[row] = s;
    }
    if (t < 64) {
        diag_l[t] = 0.f;
        float sg = params[0];
        f_reg = invN*(Yp2[t] + a1_l[t]*rp2_s + ar[t]*sg) + a1_l[t]*sg + Wbv[obase + t];
        fv[b*256 + obase + t] = f_reg;
    }
    __syncthreads();

    f32x4 accZ[4][2];
    #pragma unroll
    for (int i = 0; i < 4; ++i) { accZ[i][0] = (f32x4){0,0,0,0}; accZ[i][1] = (f32x4){0,0,0,0}; }
    #pragma unroll
    for (int ks = 0; ks < 8; ++ks) {
        bf16x8 a4[4], b2[2];
        #pragma unroll
        for (int mi = 0; mi < 4; ++mi) {
            int ol = mi*16 + lr;
            a4[mi] = __builtin_bit_cast(bf16x8, *(const u16x8*)&Ebuf[ol*256 + ((ks*32 + lg*8) ^ ((ol&7)<<3))]);
        }
        #pragma unroll
        for (int ni = 0; ni < 2; ++ni)
            b2[ni] = __builtin_bit_cast(bf16x8, *(const u16x8*)(Sb + (size_t)(wv*32+ni*16+lr)*256 + ks*32 + lg*8));
        #pragma unroll
        for (int mi = 0; mi < 4; ++mi)
            #pragma unroll
            for (int ni = 0; ni < 2; ++ni)
                accZ[mi][ni] = MFMA(a4[mi], b2[ni], accZ[mi][ni]);
    }
    #pragma unroll
    for (int mi = 0; mi < 4; ++mi)
        #pragma unroll
        for (int j = 0; j < 4; ++j) {
            int ol = mi*16 + lg*4 + j;
            float s = 0.f;
            #pragma unroll
            for (int ni = 0; ni < 2; ++ni) {
                int c2 = wv*32 + ni*16 + lr;
                s += accZ[mi][ni][j] * bf2f(Ebuf[ol*256 + (c2 ^ ((ol&7)<<3))]);
            }
            s += __shfl_xor(s, 1); s += __shfl_xor(s, 2);
            s += __shfl_xor(s, 4); s += __shfl_xor(s, 8);
            if (lr == 0) atomicAdd(&diag_l[ol], s);
        }
    __syncthreads();

    if (t < 64) {
        int o = obase + t;
        atomicAdd(&stats[o], er[t] + 4096.0f*f_reg);
        atomicAdd(&stats[256 + o], diag_l[t] + 2.0f*f_reg*er[t] + 4096.0f*f_reg*f_reg);
    }
}

// ============ kF: out = (E x + f - mu)*sc + beta + x  (bf16 Xbf input, coalesced stores) ============
__global__ __launch_bounds__(512) void kF(
    const unsigned short* __restrict__ Xbf, const unsigned short* __restrict__ Ebf,
    const float* __restrict__ fv, const float* __restrict__ stats,
    const float* __restrict__ gamma, const float* __restrict__ beta,
    float* __restrict__ out)
{
    __shared__ __align__(16) unsigned short Xs[128*256];  // 64 KB, [n][c] swz
    __shared__ float scale_l[256], shift_l[256];
    int b = blockIdx.x >> 5, n0 = (blockIdx.x & 31) * 128;
    int t = threadIdx.x, lane = t & 63, wv = t >> 6, lr = lane & 15, lg = lane >> 4;
    const float inv = 1.0f / 32768.0f;
    if (t < 256) {
        float mu  = stats[t] * inv;
        float var = stats[256 + t] * inv - mu*mu;
        float sc  = gamma[t] * rsqrtf(var + 1e-5f);
        scale_l[t] = sc;
        shift_l[t] = (fv[b*256 + t] - mu) * sc + beta[t];
    }
    {
        // stage bf16 Xbf[c][n-tile] -> Xs[n][c] (pure u16 transpose, 16 loads in flight)
        int n4 = (t & 31) * 4, c0 = (t >> 5) * 4;
        const unsigned short* xb = Xbf + (size_t)b*CIN*NN + n0 + n4;
        ushort4 u[16];
        #pragma unroll
        for (int p = 0; p < 4; ++p) {
            int c = p*64 + c0;
            u[p*4+0] = *(const ushort4*)(xb + (size_t)(c+0)*NN);
            u[p*4+1] = *(const ushort4*)(xb + (size_t)(c+1)*NN);
            u[p*4+2] = *(const ushort4*)(xb + (size_t)(c+2)*NN);
            u[p*4+3] = *(const ushort4*)(xb + (size_t)(c+3)*NN);
        }
        #pragma unroll
        for (int p = 0; p < 4; ++p) {
            int c = p*64 + c0;
            ushort4 w0 = {u[p*4].x, u[p*4+1].x, u[p*4+2].x, u[p*4+3].x};
            ushort4 w1 = {u[p*4].y, u[p*4+1].y, u[p*4+2].y, u[p*4+3].y};
            ushort4 w2 = {u[p*4].z, u[p*4+1].z, u[p*4+2].z, u[p*4+3].z};
            ushort4 w3 = {u[p*4].w, u[p*4+1].w, u[p*4+2].w, u[p*4+3].w};
            *(ushort4*)&Xs[(n4+0)*256 + (c ^ (((n4+0)&7)<<3))] = w0;
            *(ushort4*)&Xs[(n4+1)*256 + (c ^ (((n4+1)&7)<<3))] = w1;
            *(ushort4*)&Xs[(n4+2)*256 + (c ^ (((n4+2)&7)<<3))] = w2;
            *(ushort4*)&Xs[(n4+3)*256 + (c ^ (((n4+3)&7)<<3))] = w3;
        }
    }
    __syncthreads();

    int wn = wv >> 2, wo = wv & 3;
    int nb = wn*64, ob = wo*64;
    const unsigned short* Eb = Ebf + (size_t)b*65536;
    f32x4 acc[4][4];   // [oi][ni]
    #pragma unroll
    for (int i = 0; i < 4; ++i)
        #pragma unroll
        for (int j = 0; j < 4; ++j) acc[i][j] = (f32x4){0,0,0,0};

    #pragma unroll
    for (int ks = 0; ks < 8; ++ks) {
        bf16x8 xf[4], ef[4];
        #pragma unroll
        for (int ni = 0; ni < 4; ++ni) {
            int n = nb + ni*16 + lr;
            xf[ni] = __builtin_bit_cast(bf16x8, *(const u16x8*)&Xs[(n*256 + ks*32 + lg*8) ^ ((n&7)<<3)]);
        }
        #pragma unroll
        for (int oi = 0; oi < 4; ++oi) {
            int o = ob + oi*16 + lr;
            ef[oi] = __builtin_bit_cast(bf16x8, *(const u16x8*)(Eb + (size_t)o*256 + ks*32 + lg*8));
        }
        #pragma unroll
        for (int oi = 0; oi < 4; ++oi)
            #pragma unroll
            for (int ni = 0; ni < 4; ++ni)
                acc[oi][ni] = MFMA(ef[oi], xf[ni], acc[oi][ni]);
    }

    float* op = out + (size_t)b*CIN*NN + n0;
    #pragma unroll
    for (int oi = 0; oi < 4; ++oi) {
        #pragma unroll
        for (int j = 0; j < 4; ++j) {
            int o = ob + oi*16 + lg*4 + j;
            float sc = scale_l[o], sh = shift_l[o];
            #pragma unroll
            for (int ni = 0; ni < 4; ++ni) {
                int n = nb + ni*16 + lr;
                float val = acc[oi][ni][j]*sc + sh + bf2f(Xs[(n*256 + (o ^ ((n&7)<<3)))]);
                op[(size_t)o*NN + n] = val;
            }
        }
    }
}

extern "C" void kernel_launch(void* const* d_in, const int* in_sizes, int n_in,
                              void* d_out, int out_size, void* d_ws, size_t ws_size,
                              hipStream_t stream)
{
    (void)in_sizes; (void)n_in; (void)out_size; (void)ws_size;
    const float* x     = (const float*)d_in[0];
    const float* gw    = (const float*)d_in[1];
    const float* gb    = (const float*)d_in[2];
    const float* tw    = (const float*)d_in[3];
    const float* tb    = (const float*)d_in[4];
    const float* pw    = (const float*)d_in[5];
    const float* pb    = (const float*)d_in[6];
    const float* Ww    = (const float*)d_in[7];
    const float* Wb    = (const float*)d_in[8];
    const float* gamma = (const float*)d_in[9];
    const float* beta  = (const float*)d_in[10];
    float* out = (float*)d_out;

    char* ws = (char*)d_ws;
    unsigned short* Sp  = (unsigned short*)(ws + 0);          // 16 MB
    unsigned short* Xbf = (unsigned short*)(ws + 16777216);   // 16 MB
    float* Rp           = (float*)(ws + 33554432);            // 128 KB
    unsigned short* Sbf = (unsigned short*)(ws + 33685504);   // 1 MB
    float* rv           = (float*)(ws + 34734080);            // 8 KB
    unsigned short* Abf = (unsigned short*)(ws + 34742272);   // 128 KB
    unsigned short* CmT = (unsigned short*)(ws + 34873344);   // 128 KB
    unsigned short* Ebf = (unsigned short*)(ws + 35004416);   // 1 MB
    float* fv           = (float*)(ws + 36052992);            // 8 KB
    float* a1           = (float*)(ws + 36061184);            // 1 KB
    float* c1v          = (float*)(ws + 36062208);            // 1 KB
    float* p2           = (float*)(ws + 36063232);            // 1 KB
    float* params       = (float*)(ws + 36064256);            // 64 B
    float* stats        = (float*)(ws + 36064320);            // 2 KB

    kA<<<130, 512, 0, stream>>>(x, Ww, gw, tw, pw, gb, pb, tb,
                                Sp, Rp, Xbf, Abf, CmT, a1, c1v, p2, params, stats);
    kR<<<136, 512, 0, stream>>>(Sp, Rp, Sbf, rv);
    kE<<<32,  512, 0, stream>>>(Sbf, rv, Abf, CmT, a1, c1v, p2, params, Wb, Ebf, fv, stats);
    kF<<<256, 512, 0, stream>>>(Xbf, Ebf, fv, stats, gamma, beta, out);
}

// Round 13
// 82.187 us; speedup vs baseline: 1.2275x; 1.0054x over previous
//
#include <hip/hip_runtime.h>
#include <hip/hip_bf16.h>
#include <stdint.h>

#define BB   8
#define CIN  256
#define COUT 128
#define NN   4096

using f32x4  = __attribute__((ext_vector_type(4))) float;
using bf16x8 = __attribute__((ext_vector_type(8))) __bf16;
using u16x8  = __attribute__((ext_vector_type(8))) unsigned short;

static __device__ __forceinline__ unsigned short f2bf(float f) {
    unsigned int u = __builtin_bit_cast(unsigned int, f);
    u += 0x7FFFu + ((u >> 16) & 1u);
    return (unsigned short)(u >> 16);
}
static __device__ __forceinline__ float bf2f(unsigned short u) {
    return __builtin_bit_cast(float, (unsigned int)u << 16);
}
static __device__ __forceinline__ ushort4 pack4(float a, float b, float c, float d) {
    ushort4 r; r.x=f2bf(a); r.y=f2bf(b); r.z=f2bf(c); r.w=f2bf(d); return r;
}
#define MFMA(a,b,c) __builtin_amdgcn_mfma_f32_16x16x32_bf16((a),(b),(c),0,0,0)

static __device__ __forceinline__ int sw256(int r, int c) { return (r*256 + c) ^ ((r&7)<<3); }
static __device__ __forceinline__ int sw128(int r, int c) { return (r*128 + c) ^ ((r&7)<<3); }

// ============ kA: 130 blocks x 512, __launch_bounds__(512,2) -> 256 VGPR budget.
//   0-127: Gram partials Sp[bid] (bf16) + Rp + bf16 x copy Xbf[b][c][n]
//   128  : Abf = Ww*Gw, a1 = Ww*gb, zero stats
//   129  : CmT = Tw^T*Pw, c1v = Tw^T*pb, p2 = Pw^T*tb, sigma ============
__global__ __launch_bounds__(512, 2) void kA(
    const float* __restrict__ x,
    const float* __restrict__ Wwf, const float* __restrict__ gwf,
    const float* __restrict__ twf, const float* __restrict__ pwf,
    const float* __restrict__ gbv, const float* __restrict__ pbv, const float* __restrict__ tbv,
    unsigned short* __restrict__ Sp, float* __restrict__ Rp,
    unsigned short* __restrict__ Xbf,
    unsigned short* __restrict__ Abf, unsigned short* __restrict__ CmT,
    float* __restrict__ a1, float* __restrict__ c1v, float* __restrict__ p2,
    float* __restrict__ params, float* __restrict__ stats)
{
    __shared__ __align__(16) unsigned short SH[65536];   // 128 KB
    int bid = blockIdx.x;
    int t = threadIdx.x, lane = t & 63, wv = t >> 6;
    int lr = lane & 15, lg = lane >> 4;

    if (bid < 128) {
        int b = bid >> 4, ch = bid & 15;
        int n0 = ch * 256;
        const float* xb = x + (size_t)b*CIN*NN + n0 + lane*4;
        unsigned short* xtb = Xbf + (size_t)b*CIN*NN + n0 + lane*4;
        // single-batch staging: all 32 loads in flight (v[32]=128 VGPR, disjoint from acc lifetime)
        {
            float4 v[32];
            #pragma unroll
            for (int i = 0; i < 32; ++i) {
                int c = wv*32 + i;
                v[i] = *(const float4*)(xb + (size_t)c*NN);
            }
            #pragma unroll
            for (int i = 0; i < 32; ++i) {
                int c = wv*32 + i;
                ushort4 pk = pack4(v[i].x, v[i].y, v[i].z, v[i].w);
                *(ushort4*)&SH[sw256(c, lane*4)] = pk;
                *(ushort4*)(xtb + (size_t)c*NN) = pk;
            }
        }
        __syncthreads();

        int wr = wv >> 1, wc = wv & 1;      // 4x2: tile 64 x 128
        f32x4 acc[4][8];
        #pragma unroll
        for (int i = 0; i < 4; ++i)
            #pragma unroll
            for (int j = 0; j < 8; ++j) acc[i][j] = (f32x4){0.f,0.f,0.f,0.f};
        #pragma unroll
        for (int ks = 0; ks < 8; ++ks) {
            bf16x8 af[4], bfr[8];
            #pragma unroll
            for (int mi = 0; mi < 4; ++mi) {
                int row = wr*64 + mi*16 + lr;
                af[mi] = __builtin_bit_cast(bf16x8, *(const u16x8*)&SH[sw256(row, ks*32 + lg*8)]);
            }
            #pragma unroll
            for (int ni = 0; ni < 8; ++ni) {
                int row = wc*128 + ni*16 + lr;
                bfr[ni] = __builtin_bit_cast(bf16x8, *(const u16x8*)&SH[sw256(row, ks*32 + lg*8)]);
            }
            #pragma unroll
            for (int mi = 0; mi < 4; ++mi)
                #pragma unroll
                for (int ni = 0; ni < 8; ++ni)
                    acc[mi][ni] = MFMA(af[mi], bfr[ni], acc[mi][ni]);
        }
        // row-sums from staged LDS (off the load critical path)
        if (t < 256) {
            float s = 0.f;
            #pragma unroll
            for (int q = 0; q < 32; ++q) {
                u16x8 vv = *(const u16x8*)&SH[sw256(t, q*8)];
                #pragma unroll
                for (int e = 0; e < 8; ++e) s += bf2f(vv[e]);
            }
            Rp[bid*256 + t] = s;
        }
        __syncthreads();   // all SH reads complete before overwrite
        // dump acc -> SH (swizzled)
        #pragma unroll
        for (int mi = 0; mi < 4; ++mi)
            #pragma unroll
            for (int ni = 0; ni < 8; ++ni)
                #pragma unroll
                for (int j = 0; j < 4; ++j) {
                    int c1 = wr*64 + mi*16 + lg*4 + j;
                    int c2 = wc*128 + ni*16 + lr;
                    SH[sw256(c1, c2)] = f2bf(acc[mi][ni][j]);
                }
        __syncthreads();
        // coalesced u16x8 store: 512B contiguous per row
        unsigned short* dst = Sp + (size_t)bid * 65536;
        #pragma unroll
        for (int i = t; i < 8192; i += 512) {
            int row = i >> 5, q = i & 31;
            *(u16x8*)(dst + row*256 + ((q ^ (row&7)) * 8)) = *(const u16x8*)&SH[row*256 + q*8];
        }
        return;
    }

    // ---- weight precompute blocks ----
    unsigned short* Ls = SH;
    unsigned short* Rs = SH + 32768;
    if (bid == 128) {
        for (int i = t; i < 8192; i += 512) {
            int flat = i*4, r = flat >> 7, c = flat & 127;
            float4 f = *(const float4*)(Wwf + flat);
            *(ushort4*)&Ls[sw128(r, c)] = pack4(f.x, f.y, f.z, f.w);
        }
        {
            int c = lane * 4;  int k4 = wv * 4;
            #pragma unroll
            for (int rep = 0; rep < 4; ++rep) {
                int kb = rep*32 + k4;
                float4 f0 = *(const float4*)(gwf + (size_t)(kb+0)*256 + c);
                float4 f1 = *(const float4*)(gwf + (size_t)(kb+1)*256 + c);
                float4 f2 = *(const float4*)(gwf + (size_t)(kb+2)*256 + c);
                float4 f3 = *(const float4*)(gwf + (size_t)(kb+3)*256 + c);
                *(ushort4*)&Rs[sw128(c+0, kb)] = pack4(f0.x, f1.x, f2.x, f3.x);
                *(ushort4*)&Rs[sw128(c+1, kb)] = pack4(f0.y, f1.y, f2.y, f3.y);
                *(ushort4*)&Rs[sw128(c+2, kb)] = pack4(f0.z, f1.z, f2.z, f3.z);
                *(ushort4*)&Rs[sw128(c+3, kb)] = pack4(f0.w, f1.w, f2.w, f3.w);
            }
        }
        if (t < 512) stats[t] = 0.f;
    } else {
        {
            int c = lane * 4;  int k4 = wv * 4;
            #pragma unroll
            for (int rep = 0; rep < 4; ++rep) {
                int kb = rep*32 + k4;
                float4 f0 = *(const float4*)(twf + (size_t)(kb+0)*256 + c);
                float4 f1 = *(const float4*)(twf + (size_t)(kb+1)*256 + c);
                float4 f2 = *(const float4*)(twf + (size_t)(kb+2)*256 + c);
                float4 f3 = *(const float4*)(twf + (size_t)(kb+3)*256 + c);
                *(ushort4*)&Ls[sw128(c+0, kb)] = pack4(f0.x, f1.x, f2.x, f3.x);
                *(ushort4*)&Ls[sw128(c+1, kb)] = pack4(f0.y, f1.y, f2.y, f3.y);
                *(ushort4*)&Ls[sw128(c+2, kb)] = pack4(f0.z, f1.z, f2.z, f3.z);
                *(ushort4*)&Ls[sw128(c+3, kb)] = pack4(f0.w, f1.w, f2.w, f3.w);
                float4 g0 = *(const float4*)(pwf + (size_t)(kb+0)*256 + c);
                float4 g1 = *(const float4*)(pwf + (size_t)(kb+1)*256 + c);
                float4 g2 = *(const float4*)(pwf + (size_t)(kb+2)*256 + c);
                float4 g3 = *(const float4*)(pwf + (size_t)(kb+3)*256 + c);
                *(ushort4*)&Rs[sw128(c+0, kb)] = pack4(g0.x, g1.x, g2.x, g3.x);
                *(ushort4*)&Rs[sw128(c+1, kb)] = pack4(g0.y, g1.y, g2.y, g3.y);
                *(ushort4*)&Rs[sw128(c+2, kb)] = pack4(g0.z, g1.z, g2.z, g3.z);
                *(ushort4*)&Rs[sw128(c+3, kb)] = pack4(g0.w, g1.w, g2.w, g3.w);
            }
        }
    }
    __syncthreads();

    int wr = wv >> 2, wc = wv & 3;      // 2x4: tile 128 x 64
    f32x4 acc[8][4];
    #pragma unroll
    for (int i = 0; i < 8; ++i)
        #pragma unroll
        for (int j = 0; j < 4; ++j) acc[i][j] = (f32x4){0.f,0.f,0.f,0.f};
    #pragma unroll
    for (int ks = 0; ks < 4; ++ks) {
        bf16x8 af[8], bfr[4];
        #pragma unroll
        for (int mi = 0; mi < 8; ++mi) {
            int r = wr*128 + mi*16 + lr;
            af[mi] = __builtin_bit_cast(bf16x8, *(const u16x8*)&Ls[sw128(r, ks*32 + lg*8)]);
        }
        #pragma unroll
        for (int ni = 0; ni < 4; ++ni) {
            int c = wc*64 + ni*16 + lr;
            bfr[ni] = __builtin_bit_cast(bf16x8, *(const u16x8*)&Rs[sw128(c, ks*32 + lg*8)]);
        }
        #pragma unroll
        for (int mi = 0; mi < 8; ++mi)
            #pragma unroll
            for (int ni = 0; ni < 4; ++ni)
                acc[mi][ni] = MFMA(af[mi], bfr[ni], acc[mi][ni]);
    }
    unsigned short* Dst = (bid == 128) ? Abf : CmT;
    #pragma unroll
    for (int mi = 0; mi < 8; ++mi)
        #pragma unroll
        for (int ni = 0; ni < 4; ++ni)
            #pragma unroll
            for (int j = 0; j < 4; ++j) {
                int r = wr*128 + mi*16 + lg*4 + j;
                int c = wc*64 + ni*16 + lr;
                Dst[r*256 + c] = f2bf(acc[mi][ni][j]);
            }

    if (bid == 128) {
        if (t < 256) {
            float s = 0.f;
            #pragma unroll
            for (int q = 0; q < 32; ++q) {
                float4 f = *(const float4*)(Wwf + (size_t)t*128 + q*4);
                s += f.x*gbv[q*4] + f.y*gbv[q*4+1] + f.z*gbv[q*4+2] + f.w*gbv[q*4+3];
            }
            a1[t] = s;
        }
    } else {
        if (t < 256) {
            float s1 = 0.f, s2 = 0.f;
            for (int k = 0; k < 128; ++k) {
                s1 += twf[(size_t)k*256 + t] * pbv[k];
                s2 += pwf[(size_t)k*256 + t] * tbv[k];
            }
            c1v[t] = s1; p2[t] = s2;
        }
        if (t < 64) {
            float v = pbv[t]*tbv[t] + pbv[t+64]*tbv[t+64];
            #pragma unroll
            for (int off = 1; off < 64; off <<= 1) v += __shfl_xor(v, off);
            if (t == 0) params[0] = v;
        }
    }
}

// ============ kR: 136 blocks. 0-127: Sbf[b] = sum 16 partials; 128-135: rv ============
__global__ __launch_bounds__(512) void kR(
    const unsigned short* __restrict__ Sp, const float* __restrict__ Rp,
    unsigned short* __restrict__ Sbf, float* __restrict__ rv)
{
    int bid = blockIdx.x, t = threadIdx.x;
    if (bid < 128) {
        int b = bid >> 4, sl = bid & 15;
        int base = sl*4096 + t*8;
        float s[8] = {0.f,0.f,0.f,0.f,0.f,0.f,0.f,0.f};
        #pragma unroll
        for (int i = 0; i < 16; ++i) {
            u16x8 v = *(const u16x8*)(Sp + (size_t)(b*16 + i)*65536 + base);
            #pragma unroll
            for (int e = 0; e < 8; ++e) s[e] += bf2f(v[e]);
        }
        u16x8 o;
        #pragma unroll
        for (int e = 0; e < 8; ++e) o[e] = f2bf(s[e]);
        *(u16x8*)(Sbf + (size_t)b*65536 + base) = o;
    } else {
        int b = bid - 128;
        if (t < 256) {
            float s = 0.f;
            #pragma unroll
            for (int i = 0; i < 16; ++i) s += Rp[(b*16 + i)*256 + t];
            rv[b*256 + t] = s;
        }
    }
}

// ============ kE: 32 blocks (b, o-slice of 64). Y=A_sl*S; E=(Y*Cm)/N + rank-2; f; BN stats ============
__global__ __launch_bounds__(512) void kE(
    const unsigned short* __restrict__ Sbf, const float* __restrict__ rv,
    const unsigned short* __restrict__ Abf, const unsigned short* __restrict__ CmT,
    const float* __restrict__ a1g, const float* __restrict__ c1vg, const float* __restrict__ p2g,
    const float* __restrict__ params, const float* __restrict__ Wbv,
    unsigned short* __restrict__ Ebf, float* __restrict__ fv, float* __restrict__ stats)
{
    __shared__ __align__(16) unsigned short Ybuf[16384];
    __shared__ __align__(16) unsigned short Ebuf[16384];
    __shared__ float r_l[256], p2_l[256], c1v_l[256], cr[256];
    __shared__ float a1_l[64], ar[64], Yp2[64], er[64], diag_l[64];
    __shared__ float rp2_s;
    int blk = blockIdx.x;
    int b = blk >> 2, obase = (blk & 3) * 64;
    int t = threadIdx.x, lane = t & 63, wv = t >> 6;
    int lr = lane & 15, lg = lane >> 4;
    const float invN = 1.0f/4096.0f;
    const unsigned short* Sb = Sbf + (size_t)b*65536;

    if (t < 256) {
        r_l[t] = rv[b*256 + t];
        p2_l[t] = p2g[t];
        c1v_l[t] = c1vg[t];
    } else if (t < 320) {
        a1_l[t - 256] = a1g[obase + (t - 256)];
    }
    __syncthreads();

    f32x4 acc[4][2];
    #pragma unroll
    for (int i = 0; i < 4; ++i) { acc[i][0] = (f32x4){0,0,0,0}; acc[i][1] = (f32x4){0,0,0,0}; }
    const unsigned short* Arow0 = Abf + (size_t)obase*256;
    #pragma unroll
    for (int ks = 0; ks < 8; ++ks) {
        bf16x8 a4[4], b2[2];
        #pragma unroll
        for (int mi = 0; mi < 4; ++mi)
            a4[mi] = __builtin_bit_cast(bf16x8, *(const u16x8*)(Arow0 + (size_t)(mi*16+lr)*256 + ks*32 + lg*8));
        #pragma unroll
        for (int ni = 0; ni < 2; ++ni)
            b2[ni] = __builtin_bit_cast(bf16x8, *(const u16x8*)(Sb + (size_t)(wv*32+ni*16+lr)*256 + ks*32 + lg*8));
        #pragma unroll
        for (int mi = 0; mi < 4; ++mi)
            #pragma unroll
            for (int ni = 0; ni < 2; ++ni)
                acc[mi][ni] = MFMA(a4[mi], b2[ni], acc[mi][ni]);
    }
    #pragma unroll
    for (int mi = 0; mi < 4; ++mi)
        #pragma unroll
        for (int ni = 0; ni < 2; ++ni)
            #pragma unroll
            for (int j = 0; j < 4; ++j) {
                int ol = mi*16 + lg*4 + j;
                int c2 = wv*32 + ni*16 + lr;
                Ybuf[ol*256 + (c2 ^ ((ol&7)<<3))] = f2bf(acc[mi][ni][j]);
            }
    __syncthreads();

    {
        int row = t >> 3, p8 = t & 7;
        float sA = 0.f, sY = 0.f;
        const unsigned short* Ar = Abf + (size_t)(obase + row)*256 + p8*32;
        #pragma unroll
        for (int q = 0; q < 4; ++q) {
            u16x8 av = *(const u16x8*)(Ar + q*8);
            #pragma unroll
            for (int e = 0; e < 8; ++e) {
                int c = p8*32 + q*8 + e;
                sA += bf2f(av[e]) * r_l[c];
                sY += bf2f(Ybuf[row*256 + (c ^ ((row&7)<<3))]) * p2_l[c];
            }
        }
        sA += __shfl_xor(sA, 1); sA += __shfl_xor(sA, 2); sA += __shfl_xor(sA, 4);
        sY += __shfl_xor(sY, 1); sY += __shfl_xor(sY, 2); sY += __shfl_xor(sY, 4);
        if (p8 == 0) { ar[row] = sA; Yp2[row] = sY; }
    }
    if (t < 256) {
        float s = 0.f;
        const unsigned short* Cr = CmT + (size_t)t*256;
        #pragma unroll
        for (int q = 0; q < 32; ++q) {
            u16x8 v = *(const u16x8*)(Cr + q*8);
            #pragma unroll
            for (int e = 0; e < 8; ++e) s += bf2f(v[e]) * r_l[q*8 + e];
        }
        cr[t] = s;
    }
    if (t < 64) {
        float v = r_l[t*4]*p2_l[t*4] + r_l[t*4+1]*p2_l[t*4+1]
                + r_l[t*4+2]*p2_l[t*4+2] + r_l[t*4+3]*p2_l[t*4+3];
        #pragma unroll
        for (int off = 1; off < 64; off <<= 1) v += __shfl_xor(v, off);
        if (t == 0) rp2_s = v;
    }
    __syncthreads();

    f32x4 accE[4][2];
    #pragma unroll
    for (int i = 0; i < 4; ++i) { accE[i][0] = (f32x4){0,0,0,0}; accE[i][1] = (f32x4){0,0,0,0}; }
    #pragma unroll
    for (int ks = 0; ks < 8; ++ks) {
        bf16x8 a4[4], b2[2];
        #pragma unroll
        for (int mi = 0; mi < 4; ++mi) {
            int ol = mi*16 + lr;
            a4[mi] = __builtin_bit_cast(bf16x8, *(const u16x8*)&Ybuf[ol*256 + ((ks*32 + lg*8) ^ ((ol&7)<<3))]);
        }
        #pragma unroll
        for (int ni = 0; ni < 2; ++ni)
            b2[ni] = __builtin_bit_cast(bf16x8, *(const u16x8*)(CmT + (size_t)(wv*32+ni*16+lr)*256 + ks*32 + lg*8));
        #pragma unroll
        for (int mi = 0; mi < 4; ++mi)
            #pragma unroll
            for (int ni = 0; ni < 2; ++ni)
                accE[mi][ni] = MFMA(a4[mi], b2[ni], accE[mi][ni]);
    }
    unsigned short* Eb = Ebf + (size_t)b*65536;
    #pragma unroll
    for (int mi = 0; mi < 4; ++mi)
        #pragma unroll
        for (int ni = 0; ni < 2; ++ni)
            #pragma unroll
            for (int j = 0; j < 4; ++j) {
                int ol = mi*16 + lg*4 + j;
                int cp = wv*32 + ni*16 + lr;
                float e = accE[mi][ni][j]*invN + a1_l[ol]*invN*cr[cp]
                        + (invN*ar[ol] + a1_l[ol])*c1v_l[cp];
                unsigned short eb = f2bf(e);
                Ebuf[ol*256 + (cp ^ ((ol&7)<<3))] = eb;
                Eb[(size_t)(obase + ol)*256 + cp] = eb;
            }
    __syncthreads();

    float f_reg = 0.f;
    {
        int row = t >> 3, p8 = t & 7;
        float s = 0.f;
        #pragma unroll
        for (int q = 0; q < 4; ++q)
            #pragma unroll
            for (int e = 0; e < 8; ++e) {
                int c = p8*32 + q*8 + e;
                s += bf2f(Ebuf[row*256 + (c ^ ((row&7)<<3))]) * r_l[c];
            }
        s += __shfl_xor(s, 1); s += __shfl_xor(s, 2); s += __shfl_xor(s, 4);
        if (p8 == 0) er[row] = s;
    }
    if (t < 64) {
        diag_l[t] = 0.f;
        float sg = params[0];
        f_reg = invN*(Yp2[t] + a1_l[t]*rp2_s + ar[t]*sg) + a1_l[t]*sg + Wbv[obase + t];
        fv[b*256 + obase + t] = f_reg;
    }
    __syncthreads();

    f32x4 accZ[4][2];
    #pragma unroll
    for (int i = 0; i < 4; ++i) { accZ[i][0] = (f32x4){0,0,0,0}; accZ[i][1] = (f32x4){0,0,0,0}; }
    #pragma unroll
    for (int ks = 0; ks < 8; ++ks) {
        bf16x8 a4[4], b2[2];
        #pragma unroll
        for (int mi = 0; mi < 4; ++mi) {
            int ol = mi*16 + lr;
            a4[mi] = __builtin_bit_cast(bf16x8, *(const u16x8*)&Ebuf[ol*256 + ((ks*32 + lg*8) ^ ((ol&7)<<3))]);
        }
        #pragma unroll
        for (int ni = 0; ni < 2; ++ni)
            b2[ni] = __builtin_bit_cast(bf16x8, *(const u16x8*)(Sb + (size_t)(wv*32+ni*16+lr)*256 + ks*32 + lg*8));
        #pragma unroll
        for (int mi = 0; mi < 4; ++mi)
            #pragma unroll
            for (int ni = 0; ni < 2; ++ni)
                accZ[mi][ni] = MFMA(a4[mi], b2[ni], accZ[mi][ni]);
    }
    #pragma unroll
    for (int mi = 0; mi < 4; ++mi)
        #pragma unroll
        for (int j = 0; j < 4; ++j) {
            int ol = mi*16 + lg*4 + j;
            float s = 0.f;
            #pragma unroll
            for (int ni = 0; ni < 2; ++ni) {
                int c2 = wv*32 + ni*16 + lr;
                s += accZ[mi][ni][j] * bf2f(Ebuf[ol*256 + (c2 ^ ((ol&7)<<3))]);
            }
            s += __shfl_xor(s, 1); s += __shfl_xor(s, 2);
            s += __shfl_xor(s, 4); s += __shfl_xor(s, 8);
            if (lr == 0) atomicAdd(&diag_l[ol], s);
        }
    __syncthreads();

    if (t < 64) {
        int o = obase + t;
        atomicAdd(&stats[o], er[t] + 4096.0f*f_reg);
        atomicAdd(&stats[256 + o], diag_l[t] + 2.0f*f_reg*er[t] + 4096.0f*f_reg*f_reg);
    }
}

// ============ kF: out = (E x + f - mu)*sc + beta + x  (bf16 Xbf input, coalesced stores) ============
__global__ __launch_bounds__(512) void kF(
    const unsigned short* __restrict__ Xbf, const unsigned short* __restrict__ Ebf,
    const float* __restrict__ fv, const float* __restrict__ stats,
    const float* __restrict__ gamma, const float* __restrict__ beta,
    float* __restrict__ out)
{
    __shared__ __align__(16) unsigned short Xs[128*256];  // 64 KB, [n][c] swz
    __shared__ float scale_l[256], shift_l[256];
    int b = blockIdx.x >> 5, n0 = (blockIdx.x & 31) * 128;
    int t = threadIdx.x, lane = t & 63, wv = t >> 6, lr = lane & 15, lg = lane >> 4;
    const float inv = 1.0f / 32768.0f;
    if (t < 256) {
        float mu  = stats[t] * inv;
        float var = stats[256 + t] * inv - mu*mu;
        float sc  = gamma[t] * rsqrtf(var + 1e-5f);
        scale_l[t] = sc;
        shift_l[t] = (fv[b*256 + t] - mu) * sc + beta[t];
    }
    {
        // stage bf16 Xbf[c][n-tile] -> Xs[n][c] (pure u16 transpose, 16 loads in flight)
        int n4 = (t & 31) * 4, c0 = (t >> 5) * 4;
        const unsigned short* xb = Xbf + (size_t)b*CIN*NN + n0 + n4;
        ushort4 u[16];
        #pragma unroll
        for (int p = 0; p < 4; ++p) {
            int c = p*64 + c0;
            u[p*4+0] = *(const ushort4*)(xb + (size_t)(c+0)*NN);
            u[p*4+1] = *(const ushort4*)(xb + (size_t)(c+1)*NN);
            u[p*4+2] = *(const ushort4*)(xb + (size_t)(c+2)*NN);
            u[p*4+3] = *(const ushort4*)(xb + (size_t)(c+3)*NN);
        }
        #pragma unroll
        for (int p = 0; p < 4; ++p) {
            int c = p*64 + c0;
            ushort4 w0 = {u[p*4].x, u[p*4+1].x, u[p*4+2].x, u[p*4+3].x};
            ushort4 w1 = {u[p*4].y, u[p*4+1].y, u[p*4+2].y, u[p*4+3].y};
            ushort4 w2 = {u[p*4].z, u[p*4+1].z, u[p*4+2].z, u[p*4+3].z};
            ushort4 w3 = {u[p*4].w, u[p*4+1].w, u[p*4+2].w, u[p*4+3].w};
            *(ushort4*)&Xs[(n4+0)*256 + (c ^ (((n4+0)&7)<<3))] = w0;
            *(ushort4*)&Xs[(n4+1)*256 + (c ^ (((n4+1)&7)<<3))] = w1;
            *(ushort4*)&Xs[(n4+2)*256 + (c ^ (((n4+2)&7)<<3))] = w2;
            *(ushort4*)&Xs[(n4+3)*256 + (c ^ (((n4+3)&7)<<3))] = w3;
        }
    }
    __syncthreads();

    int wn = wv >> 2, wo = wv & 3;
    int nb = wn*64, ob = wo*64;
    const unsigned short* Eb = Ebf + (size_t)b*65536;
    f32x4 acc[4][4];   // [oi][ni]
    #pragma unroll
    for (int i = 0; i < 4; ++i)
        #pragma unroll
        for (int j = 0; j < 4; ++j) acc[i][j] = (f32x4){0,0,0,0};

    #pragma unroll
    for (int ks = 0; ks < 8; ++ks) {
        bf16x8 xf[4], ef[4];
        #pragma unroll
        for (int ni = 0; ni < 4; ++ni) {
            int n = nb + ni*16 + lr;
            xf[ni] = __builtin_bit_cast(bf16x8, *(const u16x8*)&Xs[(n*256 + ks*32 + lg*8) ^ ((n&7)<<3)]);
        }
        #pragma unroll
        for (int oi = 0; oi < 4; ++oi) {
            int o = ob + oi*16 + lr;
            ef[oi] = __builtin_bit_cast(bf16x8, *(const u16x8*)(Eb + (size_t)o*256 + ks*32 + lg*8));
        }
        #pragma unroll
        for (int oi = 0; oi < 4; ++oi)
            #pragma unroll
            for (int ni = 0; ni < 4; ++ni)
                acc[oi][ni] = MFMA(ef[oi], xf[ni], acc[oi][ni]);
    }

    float* op = out + (size_t)b*CIN*NN + n0;
    #pragma unroll
    for (int oi = 0; oi < 4; ++oi) {
        #pragma unroll
        for (int j = 0; j < 4; ++j) {
            int o = ob + oi*16 + lg*4 + j;
            float sc = scale_l[o], sh = shift_l[o];
            #pragma unroll
            for (int ni = 0; ni < 4; ++ni) {
                int n = nb + ni*16 + lr;
                float val = acc[oi][ni][j]*sc + sh + bf2f(Xs[(n*256 + (o ^ ((n&7)<<3)))]);
                op[(size_t)o*NN + n] = val;
            }
        }
    }
}

extern "C" void kernel_launch(void* const* d_in, const int* in_sizes, int n_in,
                              void* d_out, int out_size, void* d_ws, size_t ws_size,
                              hipStream_t stream)
{
    (void)in_sizes; (void)n_in; (void)out_size; (void)ws_size;
    const float* x     = (const float*)d_in[0];
    const float* gw    = (const float*)d_in[1];
    const float* gb    = (const float*)d_in[2];
    const float* tw    = (const float*)d_in[3];
    const float* tb    = (const float*)d_in[4];
    const float* pw    = (const float*)d_in[5];
    const float* pb    = (const float*)d_in[6];
    const float* Ww    = (const float*)d_in[7];
    const float* Wb    = (const float*)d_in[8];
    const float* gamma = (const float*)d_in[9];
    const float* beta  = (const float*)d_in[10];
    float* out = (float*)d_out;

    char* ws = (char*)d_ws;
    unsigned short* Sp  = (unsigned short*)(ws + 0);          // 16 MB
    unsigned short* Xbf = (unsigned short*)(ws + 16777216);   // 16 MB
    float* Rp           = (float*)(ws + 33554432);            // 128 KB
    unsigned short* Sbf = (unsigned short*)(ws + 33685504);   // 1 MB
    float* rv           = (float*)(ws + 34734080);            // 8 KB
    unsigned short* Abf = (unsigned short*)(ws + 34742272);   // 128 KB
    unsigned short* CmT = (unsigned short*)(ws + 34873344);   // 128 KB
    unsigned short* Ebf = (unsigned short*)(ws + 35004416);   // 1 MB
    float* fv           = (float*)(ws + 36052992);            // 8 KB
    float* a1           = (float*)(ws + 36061184);            // 1 KB
    float* c1v          = (float*)(ws + 36062208);            // 1 KB
    float* p2           = (float*)(ws + 36063232);            // 1 KB
    float* params       = (float*)(ws + 36064256);            // 64 B
    float* stats        = (float*)(ws + 36064320);            // 2 KB

    kA<<<130, 512, 0, stream>>>(x, Ww, gw, tw, pw, gb, pb, tb,
                                Sp, Rp, Xbf, Abf, CmT, a1, c1v, p2, params, stats);
    kR<<<136, 512, 0, stream>>>(Sp, Rp, Sbf, rv);
    kE<<<32,  512, 0, stream>>>(Sbf, rv, Abf, CmT, a1, c1v, p2, params, Wb, Ebf, fv, stats);
    kF<<<256, 512, 0, stream>>>(Xbf, Ebf, fv, stats, gamma, beta, out);
}